// Round 6
// baseline (642.393 us; speedup 1.0000x reference)
//
#include <hip/hip_runtime.h>
#include <hip/hip_bf16.h>
#include <cstdint>

#define IDIM 1024
#define HID  256

typedef __attribute__((ext_vector_type(4))) float f32x4;
typedef __attribute__((ext_vector_type(8))) short short8;
typedef __attribute__((ext_vector_type(4))) unsigned int u32x4;

__device__ __forceinline__ unsigned pk_bf16(float a, float b) {
  __hip_bfloat162 h = __float22bfloat162_rn(make_float2(a, b));
  unsigned r; __builtin_memcpy(&r, &h, 4); return r;
}

#define STEP_BARRIER() do { \
  asm volatile("s_waitcnt lgkmcnt(0)" ::: "memory"); \
  __builtin_amdgcn_s_barrier(); } while (0)

// ---------------------------------------------------------------------------
// Prep: W1bT[n][k] = bf16(ln_w[k] * W1[k][n]); t2[n]=sum ln_w*W1; tc1=sum ln_b*W1+b1
// ---------------------------------------------------------------------------
__global__ __launch_bounds__(256)
void prep_kernel(const float* __restrict__ W1, const float* __restrict__ lnw,
                 const float* __restrict__ lnb, const float* __restrict__ b1,
                 unsigned short* __restrict__ w1bt, float* __restrict__ t2g,
                 float* __restrict__ tc1g) {
  const int t  = threadIdx.x;
  const int ni = t & 3, kg = t >> 2;
  const int n  = blockIdx.x * 4 + ni;
  const int k0 = kg * 16;
  float s1 = 0.f, s2 = 0.f;
  unsigned pk[8];
#pragma unroll
  for (int j = 0; j < 16; j += 2) {
    const int k = k0 + j;
    const float v0 = W1[(size_t)k * HID + n];
    const float v1 = W1[(size_t)(k + 1) * HID + n];
    const float sc0 = lnw[k] * v0, sc1 = lnw[k + 1] * v1;
    s2 += sc0 + sc1;
    s1 = fmaf(lnb[k], v0, fmaf(lnb[k + 1], v1, s1));
    pk[j >> 1] = pk_bf16(sc0, sc1);
  }
  u32x4* dst = reinterpret_cast<u32x4*>(w1bt + (size_t)n * IDIM + k0);
  dst[0] = u32x4{pk[0], pk[1], pk[2], pk[3]};
  dst[1] = u32x4{pk[4], pk[5], pk[6], pk[7]};
  __shared__ float red[2][64][4];
  red[0][kg][ni] = s1; red[1][kg][ni] = s2;
  __syncthreads();
  if (t < 4) {
    float a = 0.f, b = 0.f;
    for (int i = 0; i < 64; ++i) { a += red[0][i][t]; b += red[1][i][t]; }
    const int nn = blockIdx.x * 4 + t;
    tc1g[nn] = a + b1[nn];
    t2g[nn]  = b;
  }
}

// ---------------------------------------------------------------------------
// Head. Block = 64 rows x 256 cols, 4 waves (wave w: cols w*64..+64). BK=32.
// A: global->reg (2-deep named sets) -> stats+cvt -> bf16 LDS dbuf, swizzled.
// B: w1bt (L2-resident) global->reg 2-deep.
// Sync: lgkmcnt(0)+s_barrier per step ONLY — vmcnt never drained in loop.
// Pipeline invariant at top of step s:
//   buf[s&1]=A(s); RB[s&1]=B(s); RA[(s+1)&1]=A(s+1); RB[(s+1)&1]=B(s+1).
// Prologue fills RA0=A(0)(consumed)->A(2), RA1=A(1), RB0=B(0), RB1=B(1).
// ---------------------------------------------------------------------------
__global__ __launch_bounds__(256, 3)
void head_kernel(const float* __restrict__ emb,
                 const unsigned short* __restrict__ w1bt,
                 const float* __restrict__ t2g, const float* __restrict__ tc1g,
                 const float* __restrict__ w2g, const float* __restrict__ b2g,
                 float* __restrict__ out) {
  __shared__ __align__(16) char smA[2][4096];  // [buf][row*64 + chunk*16]
  __shared__ float statsS[128];                // [row*2]: mu*rs, rs
  __shared__ float poutS[4][128];              // [wave][row*2+o]

  const int t  = threadIdx.x;
  const int l  = t & 63;
  const int w  = t >> 6;
  const int lr = l & 15;
  const int lk = l >> 4;
  const int m0 = blockIdx.x * 64;

  // A staging: lane owns row (t>>2), k-offset (t&3)*8 of each BK=32 step
  const int arow = t >> 2;                      // block-local row 0..63
  const float* const aSrc = emb + (size_t)(m0 + arow) * IDIM + (t & 3) * 8;
  const int awOff = arow * 64 + (((t & 3) ^ ((arow >> 1) & 3)) * 16);

  // A fragment read offsets (swizzled): row mi*16+lr, chunk lk
  int aROff[4];
#pragma unroll
  for (int mi = 0; mi < 4; ++mi) {
    const int r = mi * 16 + lr;
    aROff[mi] = r * 64 + ((lk ^ ((r >> 1) & 3)) * 16);
  }

  // B fragment pointers: col w*64+ni*16+lr, k-lane offset lk*8
  const unsigned short* bPtr[4];
#pragma unroll
  for (int ni = 0; ni < 4; ++ni)
    bPtr[ni] = w1bt + (size_t)(w * 64 + ni * 16 + lr) * IDIM + lk * 8;

  f32x4 acc[4][4];
#pragma unroll
  for (int i = 0; i < 4; ++i)
#pragma unroll
    for (int j = 0; j < 4; ++j) acc[i][j] = f32x4{0.f, 0.f, 0.f, 0.f};
  float sum = 0.f, ssq = 0.f;

  f32x4 RA0[2], RA1[2];
  short8 RB0[4], RB1[4];

  auto issueA = [&](f32x4* RA, int s) {
    const f32x4* p = reinterpret_cast<const f32x4*>(aSrc + (size_t)s * 32);
    RA[0] = p[0]; RA[1] = p[1];
  };
  auto issueB = [&](short8* RB, int s) {
#pragma unroll
    for (int ni = 0; ni < 4; ++ni)
      RB[ni] = *reinterpret_cast<const short8*>(bPtr[ni] + s * 32);
  };
  auto processA = [&](const f32x4* RA, int buf) {
    const f32x4 x = RA[0], y = RA[1];
    sum += ((x[0] + x[1]) + (x[2] + x[3])) + ((y[0] + y[1]) + (y[2] + y[3]));
    float q = ssq;
    q = fmaf(x[0], x[0], q); q = fmaf(x[1], x[1], q);
    q = fmaf(x[2], x[2], q); q = fmaf(x[3], x[3], q);
    q = fmaf(y[0], y[0], q); q = fmaf(y[1], y[1], q);
    q = fmaf(y[2], y[2], q); q = fmaf(y[3], y[3], q);
    ssq = q;
    const u32x4 ua = {pk_bf16(x[0], x[1]), pk_bf16(x[2], x[3]),
                      pk_bf16(y[0], y[1]), pk_bf16(y[2], y[3])};
    *reinterpret_cast<u32x4*>(&smA[buf][0] + awOff) = ua;
  };
  auto compute = [&](const short8* RB, int buf) {
    short8 av[4];
#pragma unroll
    for (int mi = 0; mi < 4; ++mi)
      av[mi] = *reinterpret_cast<const short8*>(&smA[buf][0] + aROff[mi]);
#pragma unroll
    for (int mi = 0; mi < 4; ++mi)
#pragma unroll
      for (int ni = 0; ni < 4; ++ni)
        acc[mi][ni] = __builtin_amdgcn_mfma_f32_16x16x32_bf16(av[mi], RB[ni],
                                                              acc[mi][ni], 0, 0, 0);
  };

  // prologue (establishes the loop invariant)
  issueA(RA0, 0); issueB(RB0, 0);
  issueA(RA1, 1); issueB(RB1, 1);
  processA(RA0, 0);          // consumes RA0 = A(0)
  issueA(RA0, 2);            // refill: RA0 = A(2)  (the R5 bug was omitting this)
  STEP_BARRIER();            // buf0 valid

#pragma unroll 1
  for (int s = 0; s < 32; ++s) {
    const int cs = s & 1;
    if (cs == 0) {
      compute(RB0, 0);                       // B(s), A(s)
      if (s + 1 < 32) processA(RA1, 1);      // writes A(s+1) into buf1
      if (s + 2 < 32) issueB(RB0, s + 2);
      if (s + 3 < 32) issueA(RA1, s + 3);
    } else {
      compute(RB1, 1);
      if (s + 1 < 32) processA(RA0, 0);
      if (s + 2 < 32) issueB(RB1, s + 2);
      if (s + 3 < 32) issueA(RA0, s + 3);
    }
    STEP_BARRIER();                          // lgkm only; vmcnt rides across
  }

  // stats: lane owns row arow, k-slices (t&3); reduce over the 4 k-lanes
  sum += __shfl_xor(sum, 1); sum += __shfl_xor(sum, 2);
  ssq += __shfl_xor(ssq, 1); ssq += __shfl_xor(ssq, 2);
  if ((t & 3) == 0) {
    const float mu  = sum * (1.f / 1024.f);
    const float var = ssq * (1.f / 1024.f) - mu * mu;
    const float rs  = rsqrtf(var + 1e-5f);
    statsS[arow * 2]     = mu * rs;
    statsS[arow * 2 + 1] = rs;
  }
  __syncthreads();

  // epilogue: folded-LN affine -> exact GELU -> second GEMM (256 -> 2)
  float po0[16], po1[16];
#pragma unroll
  for (int i = 0; i < 16; ++i) { po0[i] = 0.f; po1[i] = 0.f; }
#pragma unroll
  for (int ni = 0; ni < 4; ++ni) {
    const int n = w * 64 + ni * 16 + lr;
    const float t2n = t2g[n];
    const float tcn = tc1g[n];
    const float w20 = w2g[n * 2];
    const float w21 = w2g[n * 2 + 1];
#pragma unroll
    for (int mi = 0; mi < 4; ++mi) {
#pragma unroll
      for (int j = 0; j < 4; ++j) {
        const int r = mi * 16 + lk * 4 + j;
        const float mrs = statsS[r * 2];
        const float rs  = statsS[r * 2 + 1];
        const float z  = fmaf(rs, acc[mi][ni][j], fmaf(-mrs, t2n, tcn));
        const float hh = 0.5f * z * (1.f + erff(z * 0.70710678118654752f));
        po0[mi * 4 + j] = fmaf(hh, w20, po0[mi * 4 + j]);
        po1[mi * 4 + j] = fmaf(hh, w21, po1[mi * 4 + j]);
      }
    }
  }
#pragma unroll
  for (int i = 0; i < 16; ++i) {
#pragma unroll
    for (int d = 1; d < 16; d <<= 1) {
      po0[i] += __shfl_xor(po0[i], d);
      po1[i] += __shfl_xor(po1[i], d);
    }
  }
  if (lr == 0) {
#pragma unroll
    for (int mi = 0; mi < 4; ++mi)
#pragma unroll
      for (int j = 0; j < 4; ++j) {
        const int r = mi * 16 + lk * 4 + j;
        poutS[w][r * 2 + 0] = po0[mi * 4 + j];
        poutS[w][r * 2 + 1] = po1[mi * 4 + j];
      }
  }
  __syncthreads();
  if (t < 128) {
    const int r = t >> 1, o = t & 1;
    const float v = poutS[0][r * 2 + o] + poutS[1][r * 2 + o] +
                    poutS[2][r * 2 + o] + poutS[3][r * 2 + o];
    out[(size_t)(m0 + r) * 2 + o] = v + b2g[o];
  }
}

extern "C" void kernel_launch(void* const* d_in, const int* in_sizes, int n_in,
                              void* d_out, int out_size, void* d_ws, size_t ws_size,
                              hipStream_t stream) {
  const float* emb = (const float*)d_in[0];
  const float* lnw = (const float*)d_in[1];
  const float* lnb = (const float*)d_in[2];
  const float* W1  = (const float*)d_in[3];
  const float* b1  = (const float*)d_in[4];
  const float* W2  = (const float*)d_in[5];
  const float* b2  = (const float*)d_in[6];
  float* out = (float*)d_out;

  unsigned short* w1bt = (unsigned short*)d_ws;  // 512 KiB
  float* t2g  = (float*)((char*)d_ws + 524288);
  float* tc1g = (float*)((char*)d_ws + 524288 + 1024);

  prep_kernel<<<64, 256, 0, stream>>>(W1, lnw, lnb, b1, w1bt, t2g, tc1g);
  head_kernel<<<65536 / 64, 256, 0, stream>>>(emb, w1bt, t2g, tc1g, W2, b2, out);
}

// Round 7
// 125.524 us; speedup vs baseline: 5.1177x; 5.1177x over previous
//
#include <hip/hip_runtime.h>
#include <hip/hip_bf16.h>
#include <cstdint>

#define IDIM 1024
#define HID  256

typedef __attribute__((ext_vector_type(4))) float f32x4;
typedef __attribute__((ext_vector_type(8))) short short8;
typedef __attribute__((ext_vector_type(4))) unsigned int u32x4;

__device__ __forceinline__ unsigned pk_bf16(float a, float b) {
  __hip_bfloat162 h = __float22bfloat162_rn(make_float2(a, b));
  unsigned r; __builtin_memcpy(&r, &h, 4); return r;
}

__device__ __forceinline__ void gl2lds16(const void* src, void* dst) {
  __builtin_amdgcn_global_load_lds(
      reinterpret_cast<const __attribute__((address_space(1))) unsigned int*>(
          reinterpret_cast<uintptr_t>(src)),
      reinterpret_cast<__attribute__((address_space(3))) unsigned int*>(
          reinterpret_cast<uintptr_t>(dst)),
      16, 0, 0);
}

// barrier only (protects LDS-buffer reuse; no waitcnt)
#define SYNC1() do {                       \
  __builtin_amdgcn_sched_barrier(0);       \
  __builtin_amdgcn_s_barrier();            \
  __builtin_amdgcn_sched_barrier(0); } while (0)

// counted vmcnt + lgkm drain + barrier (tile handoff). No "memory" clobber;
// sched_barrier(0) pins ordering (guide rule #18).
#define SYNC2(N) do {                                  \
  __builtin_amdgcn_sched_barrier(0);                   \
  asm volatile("s_waitcnt vmcnt(" #N ") lgkmcnt(0)");  \
  __builtin_amdgcn_sched_barrier(0);                   \
  __builtin_amdgcn_s_barrier();                        \
  __builtin_amdgcn_sched_barrier(0); } while (0)

// ---------------------------------------------------------------------------
// Prep: w1t = per-K-step tiled, transposed, ln_w-scaled bf16 W1.
//   elem (n, k) -> w1t[ ((k>>5)*256 + n)*32 + (k&31) ]
//   t2[n] = sum_k ln_w[k]*W1[k][n]; tc1[n] = sum_k ln_b[k]*W1[k][n] + b1[n]
// ---------------------------------------------------------------------------
__global__ __launch_bounds__(256)
void prep_kernel(const float* __restrict__ W1, const float* __restrict__ lnw,
                 const float* __restrict__ lnb, const float* __restrict__ b1,
                 unsigned short* __restrict__ w1t, float* __restrict__ t2g,
                 float* __restrict__ tc1g) {
  const int t  = threadIdx.x;
  const int ni = t & 3, kg = t >> 2;     // kg: 16-wide k-group 0..63
  const int n  = blockIdx.x * 4 + ni;
  const int k0 = kg * 16;
  float s1 = 0.f, s2 = 0.f;
  unsigned pk[8];
#pragma unroll
  for (int j = 0; j < 16; j += 2) {
    const int k = k0 + j;
    const float v0 = W1[(size_t)k * HID + n];
    const float v1 = W1[(size_t)(k + 1) * HID + n];
    const float sc0 = lnw[k] * v0, sc1 = lnw[k + 1] * v1;
    s2 += sc0 + sc1;
    s1 = fmaf(lnb[k], v0, fmaf(lnb[k + 1], v1, s1));
    pk[j >> 1] = pk_bf16(sc0, sc1);
  }
  const int sT = kg >> 1, kk0 = (kg & 1) * 16;
  u32x4* dst = reinterpret_cast<u32x4*>(w1t + ((size_t)sT * 256 + n) * 32 + kk0);
  dst[0] = u32x4{pk[0], pk[1], pk[2], pk[3]};
  dst[1] = u32x4{pk[4], pk[5], pk[6], pk[7]};
  __shared__ float red[2][64][4];
  red[0][kg][ni] = s1; red[1][kg][ni] = s2;
  __syncthreads();
  if (t < 4) {
    float a = 0.f, b = 0.f;
    for (int i = 0; i < 64; ++i) { a += red[0][i][t]; b += red[1][i][t]; }
    const int nn = blockIdx.x * 4 + t;
    tc1g[nn] = a + b1[nn];
    t2g[nn]  = b;
  }
}

// ---------------------------------------------------------------------------
// Head. Block = 64 rows x 256 cols, 4 waves (wave w: cols w*64..+64). BK=32,
// 32 K-steps, everything double-buffered 2-deep:
//   A: global->named f32x4 regs (macro, no arrays) -> stats+cvt -> bf16 LDS
//   B: per-step-contiguous w1t tiles via global_load_lds (4x 1KiB per wave)
// Per step: SYNC1 (barrier; buf reuse) ... issues(s+2) ... writeA(s+1) ...
// SYNC2(6) (B(s+1) landed; A-ds_writes drained). vmcnt never drained to 0
// until the tail. All LDS access patterns contiguous per wave (conflict-free).
// ---------------------------------------------------------------------------
__global__ __launch_bounds__(256, 3)
void head_kernel(const float* __restrict__ emb,
                 const unsigned short* __restrict__ w1t,
                 const float* __restrict__ t2g, const float* __restrict__ tc1g,
                 const float* __restrict__ w2g, const float* __restrict__ b2g,
                 float* __restrict__ out) {
  __shared__ __align__(16) char smA[2][4096];    // [buf][row*64 + koff*4B->16B]
  __shared__ __align__(16) char smB[2][16384];   // [buf][n*64 + chunk*16]
  __shared__ float statsS[128];                  // [row*2]: mu*rs, rs
  __shared__ float poutS[4][128];                // [wave][row*2+o]

  const int t  = threadIdx.x;
  const int l  = t & 63;
  const int w  = t >> 6;
  const int lr = l & 15;
  const int lk = l >> 4;
  const int m0 = blockIdx.x * 64;

  // A staging: thread owns row ar=t>>2, k-offset (t&3)*8 of each BK=32 step
  const int ar = t >> 2;
  const float* const aSrc = emb + (size_t)(m0 + ar) * IDIM + (t & 3) * 8;
  const int awByte = ar * 64 + (t & 3) * 16;

  // B staging: per-lane source inside the contiguous 16-KiB step tile
  const unsigned short* const bSrc =
      w1t + ((size_t)w * 64 + (l >> 2)) * 32 + (l & 3) * 8;

  f32x4 acc[4][4];
#pragma unroll
  for (int i = 0; i < 4; ++i)
#pragma unroll
    for (int j = 0; j < 4; ++j) acc[i][j] = f32x4{0.f, 0.f, 0.f, 0.f};
  float sum = 0.f, ssq = 0.f;

  f32x4 fa0a, fa0b, fa1a, fa1b;  // named pipeline regs (no arrays!)

#define ISSUE_A(d0, d1, s) do {                                           \
    const f32x4* _p = reinterpret_cast<const f32x4*>(aSrc + (size_t)(s) * 32); \
    d0 = _p[0]; d1 = _p[1]; } while (0)

#define ISSUE_B(s, buf) do {                                              \
    const unsigned short* _s = bSrc + (size_t)(s) * 8192;                 \
    char* _d = smB[buf] + w * 4096;                                       \
    gl2lds16(_s,        _d);                                              \
    gl2lds16(_s +  512, _d + 1024);                                       \
    gl2lds16(_s + 1024, _d + 2048);                                       \
    gl2lds16(_s + 1536, _d + 3072); } while (0)

#define WRITE_A(r0, r1, buf) do {                                         \
    const f32x4 _x = r0, _y = r1;                                         \
    sum += ((_x[0] + _x[1]) + (_x[2] + _x[3])) +                          \
           ((_y[0] + _y[1]) + (_y[2] + _y[3]));                           \
    float _q = ssq;                                                       \
    _q = fmaf(_x[0], _x[0], _q); _q = fmaf(_x[1], _x[1], _q);             \
    _q = fmaf(_x[2], _x[2], _q); _q = fmaf(_x[3], _x[3], _q);             \
    _q = fmaf(_y[0], _y[0], _q); _q = fmaf(_y[1], _y[1], _q);             \
    _q = fmaf(_y[2], _y[2], _q); _q = fmaf(_y[3], _y[3], _q);             \
    ssq = _q;                                                             \
    const u32x4 _ua = {pk_bf16(_x[0], _x[1]), pk_bf16(_x[2], _x[3]),      \
                       pk_bf16(_y[0], _y[1]), pk_bf16(_y[2], _y[3])};     \
    *reinterpret_cast<u32x4*>(smA[buf] + awByte) = _ua; } while (0)

#define COMPUTE(buf) do {                                                 \
    short8 av0, av1, av2, av3, bv0, bv1, bv2, bv3;                        \
    const char* _A = smA[buf];                                            \
    const char* _B = smB[buf] + (w * 64 + lr) * 64 + lk * 16;             \
    bv0 = *reinterpret_cast<const short8*>(_B);                           \
    bv1 = *reinterpret_cast<const short8*>(_B + 1024);                    \
    bv2 = *reinterpret_cast<const short8*>(_B + 2048);                    \
    bv3 = *reinterpret_cast<const short8*>(_B + 3072);                    \
    av0 = *reinterpret_cast<const short8*>(_A + (lr)      * 64 + lk * 16);\
    av1 = *reinterpret_cast<const short8*>(_A + (16 + lr) * 64 + lk * 16);\
    av2 = *reinterpret_cast<const short8*>(_A + (32 + lr) * 64 + lk * 16);\
    av3 = *reinterpret_cast<const short8*>(_A + (48 + lr) * 64 + lk * 16);\
    acc[0][0] = __builtin_amdgcn_mfma_f32_16x16x32_bf16(av0, bv0, acc[0][0], 0, 0, 0); \
    acc[0][1] = __builtin_amdgcn_mfma_f32_16x16x32_bf16(av0, bv1, acc[0][1], 0, 0, 0); \
    acc[0][2] = __builtin_amdgcn_mfma_f32_16x16x32_bf16(av0, bv2, acc[0][2], 0, 0, 0); \
    acc[0][3] = __builtin_amdgcn_mfma_f32_16x16x32_bf16(av0, bv3, acc[0][3], 0, 0, 0); \
    acc[1][0] = __builtin_amdgcn_mfma_f32_16x16x32_bf16(av1, bv0, acc[1][0], 0, 0, 0); \
    acc[1][1] = __builtin_amdgcn_mfma_f32_16x16x32_bf16(av1, bv1, acc[1][1], 0, 0, 0); \
    acc[1][2] = __builtin_amdgcn_mfma_f32_16x16x32_bf16(av1, bv2, acc[1][2], 0, 0, 0); \
    acc[1][3] = __builtin_amdgcn_mfma_f32_16x16x32_bf16(av1, bv3, acc[1][3], 0, 0, 0); \
    acc[2][0] = __builtin_amdgcn_mfma_f32_16x16x32_bf16(av2, bv0, acc[2][0], 0, 0, 0); \
    acc[2][1] = __builtin_amdgcn_mfma_f32_16x16x32_bf16(av2, bv1, acc[2][1], 0, 0, 0); \
    acc[2][2] = __builtin_amdgcn_mfma_f32_16x16x32_bf16(av2, bv2, acc[2][2], 0, 0, 0); \
    acc[2][3] = __builtin_amdgcn_mfma_f32_16x16x32_bf16(av2, bv3, acc[2][3], 0, 0, 0); \
    acc[3][0] = __builtin_amdgcn_mfma_f32_16x16x32_bf16(av3, bv0, acc[3][0], 0, 0, 0); \
    acc[3][1] = __builtin_amdgcn_mfma_f32_16x16x32_bf16(av3, bv1, acc[3][1], 0, 0, 0); \
    acc[3][2] = __builtin_amdgcn_mfma_f32_16x16x32_bf16(av3, bv2, acc[3][2], 0, 0, 0); \
    acc[3][3] = __builtin_amdgcn_mfma_f32_16x16x32_bf16(av3, bv3, acc[3][3], 0, 0, 0); \
  } while (0)

  // prologue: buf0=tile(0) (A written, B drained); A(1),B(1) in flight
  ISSUE_A(fa0a, fa0b, 0);
  ISSUE_B(0, 0);
  ISSUE_A(fa1a, fa1b, 1);
  ISSUE_B(1, 1);
  WRITE_A(fa0a, fa0b, 0);   // auto-wait vmcnt(10): A(0) only
  SYNC2(6);                 // B(0) landed; A(1),B(1) still flying

#pragma unroll 1
  for (int s = 0; s < 32; s += 2) {
    // ---- even step s (buf0) ----
    COMPUTE(0);
    SYNC1();                               // all waves done reading buf0
    if (s + 2 < 32) {
      ISSUE_A(fa0a, fa0b, s + 2);
      ISSUE_B(s + 2, 0);                   // into buf0 (safe post-SYNC1)
      WRITE_A(fa1a, fa1b, 1);              // A(s+1)->buf1; auto vmcnt(10)
      SYNC2(6);                            // B(s+1) landed
    } else {
      WRITE_A(fa1a, fa1b, 1);
      SYNC2(0);
    }
    // ---- odd step s+1 (buf1) ----
    COMPUTE(1);
    if (s + 2 >= 32) break;
    SYNC1();
    if (s + 3 < 32) {
      ISSUE_A(fa1a, fa1b, s + 3);
      ISSUE_B(s + 3, 1);
      WRITE_A(fa0a, fa0b, 0);              // A(s+2)->buf0
      SYNC2(6);
    } else {
      WRITE_A(fa0a, fa0b, 0);
      SYNC2(0);
    }
  }

  // row stats: thread owns row ar (k-slices t&3); reduce over 4 k-lanes
  sum += __shfl_xor(sum, 1); sum += __shfl_xor(sum, 2);
  ssq += __shfl_xor(ssq, 1); ssq += __shfl_xor(ssq, 2);
  if ((t & 3) == 0) {
    const float mu  = sum * (1.f / 1024.f);
    const float var = ssq * (1.f / 1024.f) - mu * mu;
    const float rs  = rsqrtf(var + 1e-5f);
    statsS[ar * 2]     = mu * rs;
    statsS[ar * 2 + 1] = rs;
  }
  __syncthreads();

  // epilogue: folded-LN affine -> exact GELU -> second GEMM (256 -> 2)
  float po0[16], po1[16];
#pragma unroll
  for (int i = 0; i < 16; ++i) { po0[i] = 0.f; po1[i] = 0.f; }
#pragma unroll
  for (int ni = 0; ni < 4; ++ni) {
    const int n = w * 64 + ni * 16 + lr;
    const float t2n = t2g[n];
    const float tcn = tc1g[n];
    const float w20 = w2g[n * 2];
    const float w21 = w2g[n * 2 + 1];
#pragma unroll
    for (int mi = 0; mi < 4; ++mi) {
#pragma unroll
      for (int j = 0; j < 4; ++j) {
        const int r = mi * 16 + lk * 4 + j;
        const float mrs = statsS[r * 2];
        const float rs  = statsS[r * 2 + 1];
        const float z  = fmaf(rs, acc[mi][ni][j], fmaf(-mrs, t2n, tcn));
        const float hh = 0.5f * z * (1.f + erff(z * 0.70710678118654752f));
        po0[mi * 4 + j] = fmaf(hh, w20, po0[mi * 4 + j]);
        po1[mi * 4 + j] = fmaf(hh, w21, po1[mi * 4 + j]);
      }
    }
  }
#pragma unroll
  for (int i = 0; i < 16; ++i) {
#pragma unroll
    for (int d = 1; d < 16; d <<= 1) {
      po0[i] += __shfl_xor(po0[i], d);
      po1[i] += __shfl_xor(po1[i], d);
    }
  }
  if (lr == 0) {
#pragma unroll
    for (int mi = 0; mi < 4; ++mi)
#pragma unroll
      for (int j = 0; j < 4; ++j) {
        const int r = mi * 16 + lk * 4 + j;
        poutS[w][r * 2 + 0] = po0[mi * 4 + j];
        poutS[w][r * 2 + 1] = po1[mi * 4 + j];
      }
  }
  __syncthreads();
  if (t < 128) {
    const int r = t >> 1, o = t & 1;
    const float v = poutS[0][r * 2 + o] + poutS[1][r * 2 + o] +
                    poutS[2][r * 2 + o] + poutS[3][r * 2 + o];
    out[(size_t)(m0 + r) * 2 + o] = v + b2g[o];
  }
}

extern "C" void kernel_launch(void* const* d_in, const int* in_sizes, int n_in,
                              void* d_out, int out_size, void* d_ws, size_t ws_size,
                              hipStream_t stream) {
  const float* emb = (const float*)d_in[0];
  const float* lnw = (const float*)d_in[1];
  const float* lnb = (const float*)d_in[2];
  const float* W1  = (const float*)d_in[3];
  const float* b1  = (const float*)d_in[4];
  const float* W2  = (const float*)d_in[5];
  const float* b2  = (const float*)d_in[6];
  float* out = (float*)d_out;

  unsigned short* w1t = (unsigned short*)d_ws;   // 512 KiB (tiled)
  float* t2g  = (float*)((char*)d_ws + 524288);
  float* tc1g = (float*)((char*)d_ws + 524288 + 1024);

  prep_kernel<<<HID / 4, 256, 0, stream>>>(W1, lnw, lnb, b1, w1t, t2g, tc1g);
  head_kernel<<<65536 / 64, 256, 0, stream>>>(emb, w1t, t2g, tc1g, W2, b2, out);
}